// Round 6
// baseline (923.578 us; speedup 1.0000x reference)
//
#include <hip/hip_runtime.h>
#include <math.h>

// ---------------------------------------------------------------------------
// Encoder_352187318911: x[N,512] -> Lin+BN+ELU -> Lin+BN+ELU -> GCN+BN+ReLU
//                       -> GCN+BN -> out[N,32]
// Biases cancel inside training-mode BatchNorm -> skipped.
// R6: BN column-stats fused into producers (no separate colstats passes),
//     CSR pair packed to 4B (src|local_dst<<24), 2x grid on bucket kernels.
// ---------------------------------------------------------------------------

typedef unsigned short ushort_t;
typedef unsigned int uint_t;
typedef float f32x4 __attribute__((ext_vector_type(4)));
typedef short bf16x8 __attribute__((ext_vector_type(8)));

constexpr int NPB = 192;    // nodes per coarse bucket (local dst fits 8 bits)
constexpr int NBMAX = 576;  // >= ceil(100k/192)=521

__device__ __forceinline__ void atomAddF(float* p, float v) {
  unsafeAtomicAdd(p, v);
}
__device__ __forceinline__ ushort_t f2b(float f) {   // fp32 -> bf16 RNE
  uint_t u = __float_as_uint(f);
  return (ushort_t)((u + 0x7FFFu + ((u >> 16) & 1u)) >> 16);
}
__device__ __forceinline__ float b2f(ushort_t b) {
  return __uint_as_float(((uint_t)b) << 16);
}

// ---- CSR phase 0: per-chunk LDS histogram -> global bucket counts ---------
__global__ __launch_bounds__(256) void bucket_count(const int* __restrict__ dst,
                                                    int* __restrict__ bcnt,
                                                    int E, int NB, int chunk) {
  __shared__ int hist[NBMAX];
  const int t = threadIdx.x;
  const int c0 = blockIdx.x * chunk;
  const int c1 = min(c0 + chunk, E);
  for (int b = t; b < NB; b += 256) hist[b] = 0;
  __syncthreads();
  for (int e = c0 + t; e < c1; e += 256) atomicAdd(&hist[dst[e] / NPB], 1);
  __syncthreads();
  for (int b = t; b < NB; b += 256)
    if (hist[b]) atomicAdd(&bcnt[b], hist[b]);
}

// ---- CSR phase 1: scan bucket counts --------------------------------------
__global__ void bucket_scan(const int* __restrict__ bcnt, int* __restrict__ bbase,
                            int* __restrict__ gcur, int NB, int E) {
  __shared__ int lds[1024];
  int t = threadIdx.x;
  int v = (t < NB) ? bcnt[t] : 0;
  lds[t] = v; __syncthreads();
  for (int off = 1; off < 1024; off <<= 1) {
    int add = (t >= off) ? lds[t - off] : 0;
    __syncthreads();
    lds[t] += add;
    __syncthreads();
  }
  if (t < NB) {
    int ex = lds[t] - v;
    bbase[t] = ex;
    gcur[t] = ex;
  }
  if (t == 0) bbase[NB] = E;
}

// ---- CSR phase 2: edges -> bucket regions, packed (src | ldst<<24) --------
__global__ __launch_bounds__(256) void csr_bucket(const int* __restrict__ src,
                                                  const int* __restrict__ dst,
                                                  int* __restrict__ gcur,
                                                  int* __restrict__ pair,
                                                  int E, int NB, int chunk) {
  __shared__ int hist[NBMAX], base[NBMAX], cnt[NBMAX];
  const int t = threadIdx.x;
  const int c0 = blockIdx.x * chunk;
  const int c1 = min(c0 + chunk, E);
  for (int b = t; b < NB; b += 256) hist[b] = 0;
  __syncthreads();
  for (int e = c0 + t; e < c1; e += 256) atomicAdd(&hist[dst[e] / NPB], 1);
  __syncthreads();
  for (int b = t; b < NB; b += 256) {
    int h = hist[b];
    base[b] = h ? atomicAdd(&gcur[b], h) : 0;
    cnt[b] = 0;
  }
  __syncthreads();
  for (int e = c0 + t; e < c1; e += 256) {
    int d = dst[e];
    int b = d / NPB;
    int off = atomicAdd(&cnt[b], 1);
    pair[base[b] + off] = src[e] | ((d - b * NPB) << 24);
  }
}

// ---- CSR phase 3: per-bucket deg+dinv+rowptr+scatter (LDS cursors) --------
__global__ __launch_bounds__(256) void bucket_node(const int* __restrict__ pair,
                                                   const int* __restrict__ bbase,
                                                   int* __restrict__ rowptr,
                                                   int* __restrict__ csr,
                                                   float* __restrict__ dinv, int N) {
  __shared__ int cnt[NPB];
  __shared__ int sb[256];
  const int b = blockIdx.x;
  const int t = threadIdx.x;
  const int n0 = b * NPB;
  const int n1 = min(n0 + NPB, N);
  const int s0 = bbase[b], s1 = bbase[b + 1];
  if (t < NPB) cnt[t] = 0;
  __syncthreads();
  for (int i = s0 + t; i < s1; i += 256) atomicAdd(&cnt[(uint_t)pair[i] >> 24], 1);
  __syncthreads();
  int v = (t < NPB) ? cnt[t] : 0;
  sb[t] = v; __syncthreads();
  for (int off = 1; off < 256; off <<= 1) {
    int add = (t >= off) ? sb[t - off] : 0;
    __syncthreads();
    sb[t] += add;
    __syncthreads();
  }
  int excl = sb[t] - v;
  if (t < n1 - n0) {
    rowptr[n0 + t] = s0 + excl;
    dinv[n0 + t] = rsqrtf((float)(v + 1));   // +1 self-loop
  }
  if (b == gridDim.x - 1 && t == 0) rowptr[N] = s1;
  __syncthreads();
  if (t < NPB) cnt[t] = s0 + excl;           // reuse as cursor
  __syncthreads();
  for (int i = s0 + t; i < s1; i += 256) {
    int p = pair[i];
    int pos = atomicAdd(&cnt[(uint_t)p >> 24], 1);
    csr[pos] = p & 0xFFFFFF;
  }
}

// ---- W1 prep: fp32 [512][128] -> bf16 transposed [128][512] ---------------
__global__ void w1_prep(const float* __restrict__ W1, ushort_t* __restrict__ Wt) {
  int idx = blockIdx.x * 256 + threadIdx.x;   // 65536 total
  int k = idx >> 7, m = idx & 127;
  Wt[m * 512 + k] = f2b(W1[idx]);
}

// ---- MFMA GEMM1 + fused column stats --------------------------------------
__global__ __launch_bounds__(256) void mfma_gemm1(
    const float* __restrict__ X, const ushort_t* __restrict__ Wt,
    float* __restrict__ Y, float* __restrict__ gsum, float* __restrict__ gsq,
    int N) {
  constexpr int SA = 72;                     // bf16 row stride: 144B = 9*16B
  __shared__ ushort_t As[128 * SA];
  __shared__ ushort_t Bs[128 * SA];
  __shared__ float cs[128], cq[128];
  const int t = threadIdx.x;
  const int w = t >> 6, lane = t & 63;
  const int ln = lane & 15, quad = lane >> 4;
  const int r0 = blockIdx.x * 128;

  f32x4 acc[2][8];
#pragma unroll
  for (int mt = 0; mt < 2; mt++)
#pragma unroll
    for (int nt = 0; nt < 8; nt++) acc[mt][nt] = (f32x4)(0.f);

  for (int k0 = 0; k0 < 512; k0 += 64) {
    float4 av[8];
#pragma unroll
    for (int j = 0; j < 8; j++) {
      int idx = j * 256 + t;
      int row = idx >> 4, col = (idx & 15) << 2;
      av[j] = (r0 + row < N) ? *(const float4*)&X[(long)(r0 + row) * 512 + k0 + col]
                             : make_float4(0.f, 0.f, 0.f, 0.f);
    }
    int4 bv[4];
#pragma unroll
    for (int j = 0; j < 4; j++) {
      int chunk = j * 256 + t;
      int row = chunk >> 3, c16 = chunk & 7;
      bv[j] = *(const int4*)&Wt[row * 512 + k0 + c16 * 8];
    }
    __syncthreads();
#pragma unroll
    for (int j = 0; j < 8; j++) {
      int idx = j * 256 + t;
      int row = idx >> 4, col = (idx & 15) << 2;
      ushort_t p[4] = {f2b(av[j].x), f2b(av[j].y), f2b(av[j].z), f2b(av[j].w)};
      *(uint2*)&As[row * SA + col] = *(uint2*)p;
    }
#pragma unroll
    for (int j = 0; j < 4; j++) {
      int chunk = j * 256 + t;
      int row = chunk >> 3, c16 = chunk & 7;
      *(int4*)&Bs[row * SA + c16 * 8] = bv[j];
    }
    __syncthreads();
#pragma unroll
    for (int kk = 0; kk < 64; kk += 32) {
      bf16x8 af[2];
#pragma unroll
      for (int mt = 0; mt < 2; mt++)
        af[mt] = *(const bf16x8*)&As[(w * 32 + mt * 16 + ln) * SA + kk + quad * 8];
#pragma unroll
      for (int nt = 0; nt < 8; nt++) {
        bf16x8 bf = *(const bf16x8*)&Bs[(nt * 16 + ln) * SA + kk + quad * 8];
#pragma unroll
        for (int mt = 0; mt < 2; mt++)
          acc[mt][nt] = __builtin_amdgcn_mfma_f32_16x16x32_bf16(af[mt], bf, acc[mt][nt], 0, 0, 0);
      }
    }
  }

  if (t < 128) { cs[t] = 0.f; cq[t] = 0.f; }
  __syncthreads();
  // epilogue: write + per-column partial stats (invalid rows have acc==0)
#pragma unroll
  for (int nt = 0; nt < 8; nt++) {
    float s = 0.f, q = 0.f;
#pragma unroll
    for (int mt = 0; mt < 2; mt++) {
#pragma unroll
      for (int r = 0; r < 4; r++) {
        float vv = acc[mt][nt][r];
        s += vv; q += vv * vv;
        int row = r0 + w * 32 + mt * 16 + quad * 4 + r;
        if (row < N) Y[(long)row * 128 + nt * 16 + ln] = vv;
      }
    }
    atomicAdd(&cs[nt * 16 + ln], s);
    atomicAdd(&cq[nt * 16 + ln], q);
  }
  __syncthreads();
  if (t < 128) {
    atomAddF(&gsum[t], cs[t]);
    atomAddF(&gsq[t], cq[t]);
  }
}

// ---- tiled fp32 GEMM (layers 2-4) -----------------------------------------
// AIN: 0 raw, 1 BN+ELU, 2 BN+ReLU on A-load
// EPI: 0 Yf fp32, 1 Yb bf16(result*dinv)
// STAT: 1 -> fused column stats into gsum/gsq
template<int K, int M, int EPI, int AIN, int STAT>
__global__ __launch_bounds__(256) void gemm_tiled(
    const float* __restrict__ X, const float* __restrict__ W,
    float* __restrict__ Yf, ushort_t* __restrict__ Yb,
    const float* __restrict__ dinv,
    const float* __restrict__ ascale, const float* __restrict__ ashift,
    float* __restrict__ gsum, float* __restrict__ gsq, int N) {
  constexpr int BM = 64, KT = 16;
  constexpr int MC = M / 16;
  constexpr int AS = 68;
  __shared__ __align__(16) float As[KT * AS];
  __shared__ __align__(16) float Bs[KT * M];
  __shared__ float cs[M], cq[M];
  const int tid = threadIdx.x;
  const int tc = tid % 16, tr = tid / 16;
  const int r0 = blockIdx.x * BM;

  float acc[4][MC];
#pragma unroll
  for (int r = 0; r < 4; r++)
#pragma unroll
    for (int c = 0; c < MC; c++) acc[r][c] = 0.f;

  const int arow = tid / 4;
  const int akoff = (tid % 4) * 4;
  const bool arowok = (r0 + arow) < N;
  const long xbase = (long)(r0 + arow) * K + akoff;
  constexpr int BLD = (KT * M) / 256;

  for (int k0 = 0; k0 < K; k0 += KT) {
    float4 av = make_float4(0.f, 0.f, 0.f, 0.f);
    if (arowok) {
      av = *(const float4*)&X[xbase + k0];
      if (AIN != 0) {
        float4 sc = *(const float4*)&ascale[k0 + akoff];
        float4 sh = *(const float4*)&ashift[k0 + akoff];
        av.x = av.x * sc.x + sh.x;
        av.y = av.y * sc.y + sh.y;
        av.z = av.z * sc.z + sh.z;
        av.w = av.w * sc.w + sh.w;
        if (AIN == 1) {
          av.x = av.x > 0.f ? av.x : (expf(av.x) - 1.f);
          av.y = av.y > 0.f ? av.y : (expf(av.y) - 1.f);
          av.z = av.z > 0.f ? av.z : (expf(av.z) - 1.f);
          av.w = av.w > 0.f ? av.w : (expf(av.w) - 1.f);
        } else {
          av.x = fmaxf(av.x, 0.f); av.y = fmaxf(av.y, 0.f);
          av.z = fmaxf(av.z, 0.f); av.w = fmaxf(av.w, 0.f);
        }
      }
    }
    float bv[BLD];
#pragma unroll
    for (int i = 0; i < BLD; i++) bv[i] = W[(long)k0 * M + i * 256 + tid];
    __syncthreads();
    As[(akoff + 0) * AS + arow] = av.x;
    As[(akoff + 1) * AS + arow] = av.y;
    As[(akoff + 2) * AS + arow] = av.z;
    As[(akoff + 3) * AS + arow] = av.w;
#pragma unroll
    for (int i = 0; i < BLD; i++) Bs[i * 256 + tid] = bv[i];
    __syncthreads();
#pragma unroll
    for (int kk = 0; kk < KT; kk++) {
      float4 a = *(const float4*)&As[kk * AS + tr * 4];
      float ar[4] = {a.x, a.y, a.z, a.w};
      float b[MC];
#pragma unroll
      for (int c = 0; c < MC; c++) b[c] = Bs[kk * M + tc * MC + c];
#pragma unroll
      for (int r = 0; r < 4; r++)
#pragma unroll
        for (int c = 0; c < MC; c++) acc[r][c] += ar[r] * b[c];
    }
  }

  if (STAT) {
    if (tid < M) { cs[tid] = 0.f; cq[tid] = 0.f; }
    __syncthreads();
  }
#pragma unroll
  for (int c = 0; c < MC; c++) {
    int col = tc * MC + c;
    float s = 0.f, q = 0.f;
#pragma unroll
    for (int r = 0; r < 4; r++) {
      int row = r0 + tr * 4 + r;
      float vv = acc[r][c];
      s += vv; q += vv * vv;     // invalid rows: acc==0, no effect
      if (row < N) {
        if (EPI == 0) Yf[(long)row * M + col] = vv;
        else          Yb[(long)row * M + col] = f2b(vv * dinv[row]);
      }
    }
    if (STAT) {
      atomicAdd(&cs[col], s);
      atomicAdd(&cq[col], q);
    }
  }
  if (STAT) {
    __syncthreads();
    if (tid < M) {
      atomAddF(&gsum[tid], cs[tid]);
      atomAddF(&gsq[tid], cq[tid]);
    }
  }
}

// ---- pull aggregation + fused column stats (grid-stride) ------------------
template<int C>
__global__ __launch_bounds__(256) void gcn_pull(const ushort_t* __restrict__ htn,
                                                const int* __restrict__ rowptr,
                                                const int* __restrict__ csr,
                                                const float* __restrict__ dinv,
                                                float* __restrict__ OUT,
                                                float* __restrict__ gsum,
                                                float* __restrict__ gsq, int N) {
  constexpr int NPBk = 256 / C;
  __shared__ float cs[C], cq[C];
  const int t = threadIdx.x;
  if (t < C) { cs[t] = 0.f; cq[t] = 0.f; }
  __syncthreads();
  const int c = t % C, g = t / C;
  float s = 0.f, q = 0.f;
  for (int node = blockIdx.x * NPBk + g; node < N; node += gridDim.x * NPBk) {
    const int st = rowptr[node], en = rowptr[node + 1];
    float acc = b2f(htn[(long)node * C + c]);   // self-loop term
    int j = st;
    for (; j + 4 <= en; j += 4) {
      int s0 = csr[j], s1 = csr[j + 1], s2 = csr[j + 2], s3 = csr[j + 3];
      float v0 = b2f(htn[(long)s0 * C + c]);
      float v1 = b2f(htn[(long)s1 * C + c]);
      float v2 = b2f(htn[(long)s2 * C + c]);
      float v3 = b2f(htn[(long)s3 * C + c]);
      acc += v0 + v1 + v2 + v3;
    }
    for (; j < en; j++) acc += b2f(htn[(long)csr[j] * C + c]);
    float val = acc * dinv[node];
    OUT[(long)node * C + c] = val;
    s += val; q += val * val;
  }
  atomicAdd(&cs[c], s);
  atomicAdd(&cq[c], q);
  __syncthreads();
  if (t < C) {
    atomAddF(&gsum[t], cs[t]);
    atomAddF(&gsq[t], cq[t]);
  }
}

__global__ void bn_finalize(const float* __restrict__ gsum, const float* __restrict__ gsq,
                            const float* __restrict__ gamma, const float* __restrict__ beta,
                            float* scale, float* shift, int C, float invN, float eps) {
  int c = threadIdx.x;
  if (c >= C) return;
  float mean = gsum[c] * invN;
  float var = fmaxf(gsq[c] * invN - mean * mean, 0.f);
  float sc = gamma[c] * rsqrtf(var + eps);
  scale[c] = sc;
  shift[c] = beta[c] - mean * sc;
}

// ---- BN apply (final layer only) ------------------------------------------
template<int C, int ACT>
__global__ __launch_bounds__(256) void bn_apply(const float* __restrict__ X, float* __restrict__ Y,
                                                const float* __restrict__ scale,
                                                const float* __restrict__ shift, long total) {
  long stride = (long)gridDim.x * 256;
  for (long i = (long)blockIdx.x * 256 + threadIdx.x; i < total; i += stride) {
    int c = (int)(i & (C - 1));
    float v = X[i] * scale[c] + shift[c];
    if (ACT == 1) v = fmaxf(v, 0.f);
    if (ACT == 2) v = v > 0.f ? v : (expf(v) - 1.f);
    Y[i] = v;
  }
}

// ---------------------------------------------------------------------------
extern "C" void kernel_launch(void* const* d_in, const int* in_sizes, int n_in,
                              void* d_out, int out_size, void* d_ws, size_t ws_size,
                              hipStream_t stream) {
  const float* x   = (const float*)d_in[0];
  const int* eidx  = (const int*)d_in[1];
  const float* W1  = (const float*)d_in[2];
  const float* g1  = (const float*)d_in[4];
  const float* be1 = (const float*)d_in[5];
  const float* W2  = (const float*)d_in[6];
  const float* g2  = (const float*)d_in[8];
  const float* be2 = (const float*)d_in[9];
  const float* Wg1 = (const float*)d_in[10];
  const float* g3  = (const float*)d_in[12];
  const float* be3 = (const float*)d_in[13];
  const float* Wg2 = (const float*)d_in[14];
  const float* g4  = (const float*)d_in[16];
  const float* be4 = (const float*)d_in[17];
  float* out = (float*)d_out;

  const int N = in_sizes[0] / 512;
  const int E = in_sizes[1] / 2;
  const int* src  = eidx;
  const int* dstp = eidx + E;
  const long Nl = N;
  const int NB = (N + NPB - 1) / NPB;

  float* ws = (float*)d_ws;
  float* h1 = ws;                        // N*128 f32 (pre-GEMM1: pair buffer)
  float* h2 = ws + Nl * 128;             // N*64 f32
  int* csr    = (int*)(ws + Nl * 192);   // E
  int* rowptr = csr + E;                 // N+1
  int* gcur   = rowptr + N + 1;          // 640
  int* bbase  = gcur + 640;              // 644
  float* dinv = (float*)(bbase + 644);   // N
  float* S    = dinv + N;
  float* sums = S;                       // 512
  float* sqs  = S + 512;                 // 512
  int* bcnt   = (int*)(S + 1024);        // 640
  float* scale = S + 1664;               // 512
  float* shift = S + 2176;               // 512
  ushort_t* Wt = (ushort_t*)(S + 2688);  // 128*512 bf16 (128 KB)

  int* pair = (int*)h1;                  // E packed ints (12.8MB)

  float* out1    = h1;                          // N*64 f32
  ushort_t* htn  = (ushort_t*)(h1 + Nl * 64);   // N*64 bf16
  ushort_t* htn2 = (ushort_t*)h2;               // N*32 bf16
  float* out2    = h2 + Nl * 32;                // N*32 f32

  // zero sums, sqs, bcnt
  hipMemsetAsync(S, 0, 1664 * sizeof(float), stream);

  const float invN = 1.0f / (float)N;
  const int gb  = (N + 63) / 64;
  const int chunk = (E + 511) / 512;

  // W1 -> bf16 transposed
  w1_prep<<<256, 256, 0, stream>>>(W1, Wt);

  // CSR + degree pipeline (no E-scale global atomics)
  bucket_count<<<512, 256, 0, stream>>>(dstp, bcnt, E, NB, chunk);
  bucket_scan<<<1, 1024, 0, stream>>>(bcnt, bbase, gcur, NB, E);
  csr_bucket<<<512, 256, 0, stream>>>(src, dstp, gcur, pair, E, NB, chunk);
  bucket_node<<<NB, 256, 0, stream>>>(pair, bbase, rowptr, csr, dinv, N);

  // encoder L1: Linear(512,128) via bf16 MFMA, stats fused
  mfma_gemm1<<<(N + 127) / 128, 256, 0, stream>>>(x, Wt, h1, sums + 0, sqs + 0, N);
  bn_finalize<<<1, 128, 0, stream>>>(sums + 0, sqs + 0, g1, be1, scale + 0, shift + 0, 128, invN, 1e-3f);

  // encoder L2: A = ELU(BN(h1)) fused; stats fused
  gemm_tiled<128, 64, 0, 1, 1><<<gb, 256, 0, stream>>>(h1, W2, h2, nullptr, nullptr,
      scale + 0, shift + 0, sums + 128, sqs + 128, N);
  bn_finalize<<<1, 128, 0, stream>>>(sums + 128, sqs + 128, g2, be2, scale + 128, shift + 128, 64, invN, 1e-3f);

  // gc1: A = ELU(BN(h2)) fused; epilogue htn = bf16(h@Wg1 * dinv)
  gemm_tiled<64, 64, 1, 1, 0><<<gb, 256, 0, stream>>>(h2, Wg1, nullptr, htn, dinv,
      scale + 128, shift + 128, nullptr, nullptr, N);
  gcn_pull<64><<<1024, 256, 0, stream>>>(htn, rowptr, csr, dinv, out1, sums + 256, sqs + 256, N);
  bn_finalize<<<1, 128, 0, stream>>>(sums + 256, sqs + 256, g3, be3, scale + 256, shift + 256, 64, invN, 1e-5f);

  // gc2: A = ReLU(BN(out1)) fused; epilogue htn2 = bf16(h@Wg2 * dinv)
  gemm_tiled<64, 32, 1, 2, 0><<<gb, 256, 0, stream>>>(out1, Wg2, nullptr, htn2, dinv,
      scale + 256, shift + 256, nullptr, nullptr, N);
  gcn_pull<32><<<1024, 256, 0, stream>>>(htn2, rowptr, csr, dinv, out2, sums + 384, sqs + 384, N);
  bn_finalize<<<1, 128, 0, stream>>>(sums + 384, sqs + 384, g4, be4, scale + 384, shift + 384, 32, invN, 1e-5f);
  bn_apply<32, 0><<<2048, 256, 0, stream>>>(out2, out, scale + 384, shift + 384, Nl * 32);
}

// Round 7
// 862.057 us; speedup vs baseline: 1.0714x; 1.0714x over previous
//
#include <hip/hip_runtime.h>
#include <math.h>

// ---------------------------------------------------------------------------
// Encoder_352187318911: x[N,512] -> Lin+BN+ELU -> Lin+BN+ELU -> GCN+BN+ReLU
//                       -> GCN+BN -> out[N,32]
// Biases cancel inside training-mode BatchNorm -> skipped.
// R7: revert pull to per-node blocks (R6 grid-stride cut TLP 25x on a
//     latency-bound gather: 190us vs <=119us). Stats for pull outputs go
//     back to separate cheap colstats passes. Pull inner loop: align + 8-wide
//     unroll with int4 csr loads.
// ---------------------------------------------------------------------------

typedef unsigned short ushort_t;
typedef unsigned int uint_t;
typedef float f32x4 __attribute__((ext_vector_type(4)));
typedef short bf16x8 __attribute__((ext_vector_type(8)));

constexpr int NPB = 192;    // nodes per coarse bucket (local dst fits 8 bits)
constexpr int NBMAX = 576;  // >= ceil(100k/192)=521

__device__ __forceinline__ void atomAddF(float* p, float v) {
  unsafeAtomicAdd(p, v);
}
__device__ __forceinline__ ushort_t f2b(float f) {   // fp32 -> bf16 RNE
  uint_t u = __float_as_uint(f);
  return (ushort_t)((u + 0x7FFFu + ((u >> 16) & 1u)) >> 16);
}
__device__ __forceinline__ float b2f(ushort_t b) {
  return __uint_as_float(((uint_t)b) << 16);
}

// ---- CSR phase 0: per-chunk LDS histogram -> global bucket counts ---------
__global__ __launch_bounds__(256) void bucket_count(const int* __restrict__ dst,
                                                    int* __restrict__ bcnt,
                                                    int E, int NB, int chunk) {
  __shared__ int hist[NBMAX];
  const int t = threadIdx.x;
  const int c0 = blockIdx.x * chunk;
  const int c1 = min(c0 + chunk, E);
  for (int b = t; b < NB; b += 256) hist[b] = 0;
  __syncthreads();
  for (int e = c0 + t; e < c1; e += 256) atomicAdd(&hist[dst[e] / NPB], 1);
  __syncthreads();
  for (int b = t; b < NB; b += 256)
    if (hist[b]) atomicAdd(&bcnt[b], hist[b]);
}

// ---- CSR phase 1: scan bucket counts --------------------------------------
__global__ void bucket_scan(const int* __restrict__ bcnt, int* __restrict__ bbase,
                            int* __restrict__ gcur, int NB, int E) {
  __shared__ int lds[1024];
  int t = threadIdx.x;
  int v = (t < NB) ? bcnt[t] : 0;
  lds[t] = v; __syncthreads();
  for (int off = 1; off < 1024; off <<= 1) {
    int add = (t >= off) ? lds[t - off] : 0;
    __syncthreads();
    lds[t] += add;
    __syncthreads();
  }
  if (t < NB) {
    int ex = lds[t] - v;
    bbase[t] = ex;
    gcur[t] = ex;
  }
  if (t == 0) bbase[NB] = E;
}

// ---- CSR phase 2: edges -> bucket regions, packed (src | ldst<<24) --------
__global__ __launch_bounds__(256) void csr_bucket(const int* __restrict__ src,
                                                  const int* __restrict__ dst,
                                                  int* __restrict__ gcur,
                                                  int* __restrict__ pair,
                                                  int E, int NB, int chunk) {
  __shared__ int hist[NBMAX], base[NBMAX], cnt[NBMAX];
  const int t = threadIdx.x;
  const int c0 = blockIdx.x * chunk;
  const int c1 = min(c0 + chunk, E);
  for (int b = t; b < NB; b += 256) hist[b] = 0;
  __syncthreads();
  for (int e = c0 + t; e < c1; e += 256) atomicAdd(&hist[dst[e] / NPB], 1);
  __syncthreads();
  for (int b = t; b < NB; b += 256) {
    int h = hist[b];
    base[b] = h ? atomicAdd(&gcur[b], h) : 0;
    cnt[b] = 0;
  }
  __syncthreads();
  for (int e = c0 + t; e < c1; e += 256) {
    int d = dst[e];
    int b = d / NPB;
    int off = atomicAdd(&cnt[b], 1);
    pair[base[b] + off] = src[e] | ((d - b * NPB) << 24);
  }
}

// ---- CSR phase 3: per-bucket deg+dinv+rowptr+scatter (LDS cursors) --------
__global__ __launch_bounds__(256) void bucket_node(const int* __restrict__ pair,
                                                   const int* __restrict__ bbase,
                                                   int* __restrict__ rowptr,
                                                   int* __restrict__ csr,
                                                   float* __restrict__ dinv, int N) {
  __shared__ int cnt[NPB];
  __shared__ int sb[256];
  const int b = blockIdx.x;
  const int t = threadIdx.x;
  const int n0 = b * NPB;
  const int n1 = min(n0 + NPB, N);
  const int s0 = bbase[b], s1 = bbase[b + 1];
  if (t < NPB) cnt[t] = 0;
  __syncthreads();
  for (int i = s0 + t; i < s1; i += 256) atomicAdd(&cnt[(uint_t)pair[i] >> 24], 1);
  __syncthreads();
  int v = (t < NPB) ? cnt[t] : 0;
  sb[t] = v; __syncthreads();
  for (int off = 1; off < 256; off <<= 1) {
    int add = (t >= off) ? sb[t - off] : 0;
    __syncthreads();
    sb[t] += add;
    __syncthreads();
  }
  int excl = sb[t] - v;
  if (t < n1 - n0) {
    rowptr[n0 + t] = s0 + excl;
    dinv[n0 + t] = rsqrtf((float)(v + 1));   // +1 self-loop
  }
  if (b == gridDim.x - 1 && t == 0) rowptr[N] = s1;
  __syncthreads();
  if (t < NPB) cnt[t] = s0 + excl;           // reuse as cursor
  __syncthreads();
  for (int i = s0 + t; i < s1; i += 256) {
    int p = pair[i];
    int pos = atomicAdd(&cnt[(uint_t)p >> 24], 1);
    csr[pos] = p & 0xFFFFFF;
  }
}

// ---- W1 prep: fp32 [512][128] -> bf16 transposed [128][512] ---------------
__global__ void w1_prep(const float* __restrict__ W1, ushort_t* __restrict__ Wt) {
  int idx = blockIdx.x * 256 + threadIdx.x;   // 65536 total
  int k = idx >> 7, m = idx & 127;
  Wt[m * 512 + k] = f2b(W1[idx]);
}

// ---- MFMA GEMM1 + fused column stats --------------------------------------
__global__ __launch_bounds__(256) void mfma_gemm1(
    const float* __restrict__ X, const ushort_t* __restrict__ Wt,
    float* __restrict__ Y, float* __restrict__ gsum, float* __restrict__ gsq,
    int N) {
  constexpr int SA = 72;                     // bf16 row stride: 144B = 9*16B
  __shared__ ushort_t As[128 * SA];
  __shared__ ushort_t Bs[128 * SA];
  __shared__ float cs[128], cq[128];
  const int t = threadIdx.x;
  const int w = t >> 6, lane = t & 63;
  const int ln = lane & 15, quad = lane >> 4;
  const int r0 = blockIdx.x * 128;

  f32x4 acc[2][8];
#pragma unroll
  for (int mt = 0; mt < 2; mt++)
#pragma unroll
    for (int nt = 0; nt < 8; nt++) acc[mt][nt] = (f32x4)(0.f);

  for (int k0 = 0; k0 < 512; k0 += 64) {
    float4 av[8];
#pragma unroll
    for (int j = 0; j < 8; j++) {
      int idx = j * 256 + t;
      int row = idx >> 4, col = (idx & 15) << 2;
      av[j] = (r0 + row < N) ? *(const float4*)&X[(long)(r0 + row) * 512 + k0 + col]
                             : make_float4(0.f, 0.f, 0.f, 0.f);
    }
    int4 bv[4];
#pragma unroll
    for (int j = 0; j < 4; j++) {
      int chunk = j * 256 + t;
      int row = chunk >> 3, c16 = chunk & 7;
      bv[j] = *(const int4*)&Wt[row * 512 + k0 + c16 * 8];
    }
    __syncthreads();
#pragma unroll
    for (int j = 0; j < 8; j++) {
      int idx = j * 256 + t;
      int row = idx >> 4, col = (idx & 15) << 2;
      ushort_t p[4] = {f2b(av[j].x), f2b(av[j].y), f2b(av[j].z), f2b(av[j].w)};
      *(uint2*)&As[row * SA + col] = *(uint2*)p;
    }
#pragma unroll
    for (int j = 0; j < 4; j++) {
      int chunk = j * 256 + t;
      int row = chunk >> 3, c16 = chunk & 7;
      *(int4*)&Bs[row * SA + c16 * 8] = bv[j];
    }
    __syncthreads();
#pragma unroll
    for (int kk = 0; kk < 64; kk += 32) {
      bf16x8 af[2];
#pragma unroll
      for (int mt = 0; mt < 2; mt++)
        af[mt] = *(const bf16x8*)&As[(w * 32 + mt * 16 + ln) * SA + kk + quad * 8];
#pragma unroll
      for (int nt = 0; nt < 8; nt++) {
        bf16x8 bf = *(const bf16x8*)&Bs[(nt * 16 + ln) * SA + kk + quad * 8];
#pragma unroll
        for (int mt = 0; mt < 2; mt++)
          acc[mt][nt] = __builtin_amdgcn_mfma_f32_16x16x32_bf16(af[mt], bf, acc[mt][nt], 0, 0, 0);
      }
    }
  }

  if (t < 128) { cs[t] = 0.f; cq[t] = 0.f; }
  __syncthreads();
#pragma unroll
  for (int nt = 0; nt < 8; nt++) {
    float s = 0.f, q = 0.f;
#pragma unroll
    for (int mt = 0; mt < 2; mt++) {
#pragma unroll
      for (int r = 0; r < 4; r++) {
        float vv = acc[mt][nt][r];
        s += vv; q += vv * vv;
        int row = r0 + w * 32 + mt * 16 + quad * 4 + r;
        if (row < N) Y[(long)row * 128 + nt * 16 + ln] = vv;
      }
    }
    atomicAdd(&cs[nt * 16 + ln], s);
    atomicAdd(&cq[nt * 16 + ln], q);
  }
  __syncthreads();
  if (t < 128) {
    atomAddF(&gsum[t], cs[t]);
    atomAddF(&gsq[t], cq[t]);
  }
}

// ---- tiled fp32 GEMM (layers 2-4) -----------------------------------------
// AIN: 0 raw, 1 BN+ELU, 2 BN+ReLU on A-load
// EPI: 0 Yf fp32, 1 Yb bf16(result*dinv)
// STAT: 1 -> fused column stats into gsum/gsq
template<int K, int M, int EPI, int AIN, int STAT>
__global__ __launch_bounds__(256) void gemm_tiled(
    const float* __restrict__ X, const float* __restrict__ W,
    float* __restrict__ Yf, ushort_t* __restrict__ Yb,
    const float* __restrict__ dinv,
    const float* __restrict__ ascale, const float* __restrict__ ashift,
    float* __restrict__ gsum, float* __restrict__ gsq, int N) {
  constexpr int BM = 64, KT = 16;
  constexpr int MC = M / 16;
  constexpr int AS = 68;
  __shared__ __align__(16) float As[KT * AS];
  __shared__ __align__(16) float Bs[KT * M];
  __shared__ float cs[M], cq[M];
  const int tid = threadIdx.x;
  const int tc = tid % 16, tr = tid / 16;
  const int r0 = blockIdx.x * BM;

  float acc[4][MC];
#pragma unroll
  for (int r = 0; r < 4; r++)
#pragma unroll
    for (int c = 0; c < MC; c++) acc[r][c] = 0.f;

  const int arow = tid / 4;
  const int akoff = (tid % 4) * 4;
  const bool arowok = (r0 + arow) < N;
  const long xbase = (long)(r0 + arow) * K + akoff;
  constexpr int BLD = (KT * M) / 256;

  for (int k0 = 0; k0 < K; k0 += KT) {
    float4 av = make_float4(0.f, 0.f, 0.f, 0.f);
    if (arowok) {
      av = *(const float4*)&X[xbase + k0];
      if (AIN != 0) {
        float4 sc = *(const float4*)&ascale[k0 + akoff];
        float4 sh = *(const float4*)&ashift[k0 + akoff];
        av.x = av.x * sc.x + sh.x;
        av.y = av.y * sc.y + sh.y;
        av.z = av.z * sc.z + sh.z;
        av.w = av.w * sc.w + sh.w;
        if (AIN == 1) {
          av.x = av.x > 0.f ? av.x : (expf(av.x) - 1.f);
          av.y = av.y > 0.f ? av.y : (expf(av.y) - 1.f);
          av.z = av.z > 0.f ? av.z : (expf(av.z) - 1.f);
          av.w = av.w > 0.f ? av.w : (expf(av.w) - 1.f);
        } else {
          av.x = fmaxf(av.x, 0.f); av.y = fmaxf(av.y, 0.f);
          av.z = fmaxf(av.z, 0.f); av.w = fmaxf(av.w, 0.f);
        }
      }
    }
    float bv[BLD];
#pragma unroll
    for (int i = 0; i < BLD; i++) bv[i] = W[(long)k0 * M + i * 256 + tid];
    __syncthreads();
    As[(akoff + 0) * AS + arow] = av.x;
    As[(akoff + 1) * AS + arow] = av.y;
    As[(akoff + 2) * AS + arow] = av.z;
    As[(akoff + 3) * AS + arow] = av.w;
#pragma unroll
    for (int i = 0; i < BLD; i++) Bs[i * 256 + tid] = bv[i];
    __syncthreads();
#pragma unroll
    for (int kk = 0; kk < KT; kk++) {
      float4 a = *(const float4*)&As[kk * AS + tr * 4];
      float ar[4] = {a.x, a.y, a.z, a.w};
      float b[MC];
#pragma unroll
      for (int c = 0; c < MC; c++) b[c] = Bs[kk * M + tc * MC + c];
#pragma unroll
      for (int r = 0; r < 4; r++)
#pragma unroll
        for (int c = 0; c < MC; c++) acc[r][c] += ar[r] * b[c];
    }
  }

  if (STAT) {
    if (tid < M) { cs[tid] = 0.f; cq[tid] = 0.f; }
    __syncthreads();
  }
#pragma unroll
  for (int c = 0; c < MC; c++) {
    int col = tc * MC + c;
    float s = 0.f, q = 0.f;
#pragma unroll
    for (int r = 0; r < 4; r++) {
      int row = r0 + tr * 4 + r;
      float vv = acc[r][c];
      s += vv; q += vv * vv;
      if (row < N) {
        if (EPI == 0) Yf[(long)row * M + col] = vv;
        else          Yb[(long)row * M + col] = f2b(vv * dinv[row]);
      }
    }
    if (STAT) {
      atomicAdd(&cs[col], s);
      atomicAdd(&cq[col], q);
    }
  }
  if (STAT) {
    __syncthreads();
    if (tid < M) {
      atomAddF(&gsum[tid], cs[tid]);
      atomAddF(&gsq[tid], cq[tid]);
    }
  }
}

// ---- pull aggregation: per-node blocks, 8-wide unrolled gather ------------
template<int C>
__global__ __launch_bounds__(256) void gcn_pull(const ushort_t* __restrict__ htn,
                                                const int* __restrict__ rowptr,
                                                const int* __restrict__ csr,
                                                const float* __restrict__ dinv,
                                                float* __restrict__ OUT, int N) {
  constexpr int NPBk = 256 / C;
  const int node = blockIdx.x * NPBk + threadIdx.x / C;
  const int c = threadIdx.x % C;
  if (node >= N) return;
  const int st = rowptr[node], en = rowptr[node + 1];
  float acc = b2f(htn[(long)node * C + c]);   // self-loop term
  int j = st;
  for (; j < en && (j & 3); j++) acc += b2f(htn[(long)csr[j] * C + c]);
  for (; j + 8 <= en; j += 8) {
    int4 i0 = *(const int4*)&csr[j];
    int4 i1 = *(const int4*)&csr[j + 4];
    float v0 = b2f(htn[(long)i0.x * C + c]);
    float v1 = b2f(htn[(long)i0.y * C + c]);
    float v2 = b2f(htn[(long)i0.z * C + c]);
    float v3 = b2f(htn[(long)i0.w * C + c]);
    float v4 = b2f(htn[(long)i1.x * C + c]);
    float v5 = b2f(htn[(long)i1.y * C + c]);
    float v6 = b2f(htn[(long)i1.z * C + c]);
    float v7 = b2f(htn[(long)i1.w * C + c]);
    acc += ((v0 + v1) + (v2 + v3)) + ((v4 + v5) + (v6 + v7));
  }
  for (; j < en; j++) acc += b2f(htn[(long)csr[j] * C + c]);
  OUT[(long)node * C + c] = acc * dinv[node];
}

// ---- BN column stats (pull outputs only) ----------------------------------
template<int C>
__global__ __launch_bounds__(256) void colstats(const float* __restrict__ H, int N,
                                                float* gsum, float* gsq) {
  constexpr int G = 256 / C;
  const int col = threadIdx.x % C, g = threadIdx.x / C;
  float s = 0.f, q = 0.f;
  for (long r = (long)blockIdx.x * G + g; r < N; r += (long)gridDim.x * G) {
    float v = H[r * C + col];
    s += v; q += v * v;
  }
  __shared__ float ls[256], lq[256];
  ls[threadIdx.x] = s; lq[threadIdx.x] = q;
  __syncthreads();
  if (threadIdx.x < C) {
#pragma unroll
    for (int i = 1; i < G; i++) { s += ls[col + i * C]; q += lq[col + i * C]; }
    atomAddF(&gsum[col], s);
    atomAddF(&gsq[col], q);
  }
}

__global__ void bn_finalize(const float* __restrict__ gsum, const float* __restrict__ gsq,
                            const float* __restrict__ gamma, const float* __restrict__ beta,
                            float* scale, float* shift, int C, float invN, float eps) {
  int c = threadIdx.x;
  if (c >= C) return;
  float mean = gsum[c] * invN;
  float var = fmaxf(gsq[c] * invN - mean * mean, 0.f);
  float sc = gamma[c] * rsqrtf(var + eps);
  scale[c] = sc;
  shift[c] = beta[c] - mean * sc;
}

// ---- BN apply (final layer only) ------------------------------------------
template<int C, int ACT>
__global__ __launch_bounds__(256) void bn_apply(const float* __restrict__ X, float* __restrict__ Y,
                                                const float* __restrict__ scale,
                                                const float* __restrict__ shift, long total) {
  long stride = (long)gridDim.x * 256;
  for (long i = (long)blockIdx.x * 256 + threadIdx.x; i < total; i += stride) {
    int c = (int)(i & (C - 1));
    float v = X[i] * scale[c] + shift[c];
    if (ACT == 1) v = fmaxf(v, 0.f);
    if (ACT == 2) v = v > 0.f ? v : (expf(v) - 1.f);
    Y[i] = v;
  }
}

// ---------------------------------------------------------------------------
extern "C" void kernel_launch(void* const* d_in, const int* in_sizes, int n_in,
                              void* d_out, int out_size, void* d_ws, size_t ws_size,
                              hipStream_t stream) {
  const float* x   = (const float*)d_in[0];
  const int* eidx  = (const int*)d_in[1];
  const float* W1  = (const float*)d_in[2];
  const float* g1  = (const float*)d_in[4];
  const float* be1 = (const float*)d_in[5];
  const float* W2  = (const float*)d_in[6];
  const float* g2  = (const float*)d_in[8];
  const float* be2 = (const float*)d_in[9];
  const float* Wg1 = (const float*)d_in[10];
  const float* g3  = (const float*)d_in[12];
  const float* be3 = (const float*)d_in[13];
  const float* Wg2 = (const float*)d_in[14];
  const float* g4  = (const float*)d_in[16];
  const float* be4 = (const float*)d_in[17];
  float* out = (float*)d_out;

  const int N = in_sizes[0] / 512;
  const int E = in_sizes[1] / 2;
  const int* src  = eidx;
  const int* dstp = eidx + E;
  const long Nl = N;
  const int NB = (N + NPB - 1) / NPB;

  float* ws = (float*)d_ws;
  float* h1 = ws;                        // N*128 f32 (pre-GEMM1: pair buffer)
  float* h2 = ws + Nl * 128;             // N*64 f32
  int* csr    = (int*)(ws + Nl * 192);   // E
  int* rowptr = csr + E;                 // N+1
  int* gcur   = rowptr + N + 1;          // 640
  int* bbase  = gcur + 640;              // 644
  float* dinv = (float*)(bbase + 644);   // N
  float* S    = dinv + N;
  float* sums = S;                       // 512
  float* sqs  = S + 512;                 // 512
  int* bcnt   = (int*)(S + 1024);        // 640
  float* scale = S + 1664;               // 512
  float* shift = S + 2176;               // 512
  ushort_t* Wt = (ushort_t*)(S + 2688);  // 128*512 bf16 (128 KB)

  int* pair = (int*)h1;                  // E packed ints (12.8MB)

  float* out1    = h1;                          // N*64 f32
  ushort_t* htn  = (ushort_t*)(h1 + Nl * 64);   // N*64 bf16
  ushort_t* htn2 = (ushort_t*)h2;               // N*32 bf16
  float* out2    = h2 + Nl * 32;                // N*32 f32

  // zero sums, sqs, bcnt
  hipMemsetAsync(S, 0, 1664 * sizeof(float), stream);

  const float invN = 1.0f / (float)N;
  const int gb  = (N + 63) / 64;
  const int chunk = (E + 511) / 512;

  // W1 -> bf16 transposed
  w1_prep<<<256, 256, 0, stream>>>(W1, Wt);

  // CSR + degree pipeline (no E-scale global atomics)
  bucket_count<<<512, 256, 0, stream>>>(dstp, bcnt, E, NB, chunk);
  bucket_scan<<<1, 1024, 0, stream>>>(bcnt, bbase, gcur, NB, E);
  csr_bucket<<<512, 256, 0, stream>>>(src, dstp, gcur, pair, E, NB, chunk);
  bucket_node<<<NB, 256, 0, stream>>>(pair, bbase, rowptr, csr, dinv, N);

  // encoder L1: Linear(512,128) via bf16 MFMA, stats fused
  mfma_gemm1<<<(N + 127) / 128, 256, 0, stream>>>(x, Wt, h1, sums + 0, sqs + 0, N);
  bn_finalize<<<1, 128, 0, stream>>>(sums + 0, sqs + 0, g1, be1, scale + 0, shift + 0, 128, invN, 1e-3f);

  // encoder L2: A = ELU(BN(h1)) fused; stats fused
  gemm_tiled<128, 64, 0, 1, 1><<<gb, 256, 0, stream>>>(h1, W2, h2, nullptr, nullptr,
      scale + 0, shift + 0, sums + 128, sqs + 128, N);
  bn_finalize<<<1, 128, 0, stream>>>(sums + 128, sqs + 128, g2, be2, scale + 128, shift + 128, 64, invN, 1e-3f);

  // gc1: A = ELU(BN(h2)) fused; epilogue htn = bf16(h@Wg1 * dinv)
  gemm_tiled<64, 64, 1, 1, 0><<<gb, 256, 0, stream>>>(h2, Wg1, nullptr, htn, dinv,
      scale + 128, shift + 128, nullptr, nullptr, N);
  gcn_pull<64><<<(N + 3) / 4, 256, 0, stream>>>(htn, rowptr, csr, dinv, out1, N);
  colstats<64><<<1024, 256, 0, stream>>>(out1, N, sums + 256, sqs + 256);
  bn_finalize<<<1, 128, 0, stream>>>(sums + 256, sqs + 256, g3, be3, scale + 256, shift + 256, 64, invN, 1e-5f);

  // gc2: A = ReLU(BN(out1)) fused; epilogue htn2 = bf16(h@Wg2 * dinv)
  gemm_tiled<64, 32, 1, 2, 0><<<gb, 256, 0, stream>>>(out1, Wg2, nullptr, htn2, dinv,
      scale + 256, shift + 256, nullptr, nullptr, N);
  gcn_pull<32><<<(N + 7) / 8, 256, 0, stream>>>(htn2, rowptr, csr, dinv, out2, N);
  colstats<32><<<1024, 256, 0, stream>>>(out2, N, sums + 384, sqs + 384);
  bn_finalize<<<1, 128, 0, stream>>>(sums + 384, sqs + 384, g4, be4, scale + 384, shift + 384, 32, invN, 1e-5f);
  bn_apply<32, 0><<<2048, 256, 0, stream>>>(out2, out, scale + 384, shift + 384, Nl * 32);
}